// Round 1
// baseline (967.873 us; speedup 1.0000x reference)
//
#include <hip/hip_runtime.h>

#define N_NODES 50000
#define IN_CH   256
#define HID_CH  64
#define N_EDGES 800000

// ---------------------------------------------------------------------------
// Kernel 1: xw = x @ W.  x[N,256] fp32, W[256,64] fp32 -> xw[N,64].
// W staged in LDS (64 KB). Each wave computes one row: lane = out channel.
// x row read as wave-uniform float4 (L1 broadcast). W read stride-1 across
// 64 lanes = 2-way bank aliasing = free.
// ---------------------------------------------------------------------------
__global__ __launch_bounds__(256) void gemm_kernel(const float* __restrict__ x,
                                                   const float* __restrict__ W,
                                                   float* __restrict__ xw) {
    __shared__ float Wl[IN_CH * HID_CH]; // 64 KB
    for (int i = threadIdx.x; i < (IN_CH * HID_CH) / 4; i += 256) {
        ((float4*)Wl)[i] = ((const float4*)W)[i];
    }
    __syncthreads();

    const int wave = threadIdx.x >> 6;
    const int lane = threadIdx.x & 63;   // output channel

    for (int row = blockIdx.x * 4 + wave; row < N_NODES; row += gridDim.x * 4) {
        const float4* xr = (const float4*)(x + (size_t)row * IN_CH);
        float acc = 0.f;
        #pragma unroll 8
        for (int k4 = 0; k4 < IN_CH / 4; ++k4) {
            const float4 xv = xr[k4];
            const int k = k4 * 4;
            acc += xv.x * Wl[(k + 0) * HID_CH + lane];
            acc += xv.y * Wl[(k + 1) * HID_CH + lane];
            acc += xv.z * Wl[(k + 2) * HID_CH + lane];
            acc += xv.w * Wl[(k + 3) * HID_CH + lane];
        }
        xw[(size_t)row * HID_CH + lane] = acc;
    }
}

// ---------------------------------------------------------------------------
// Kernel 2: scatter-add over edges. 16 threads per edge, float4 payload each.
// out must be zeroed beforehand (hipMemsetAsync).
// ---------------------------------------------------------------------------
__global__ __launch_bounds__(256) void scatter_kernel(const float* __restrict__ xw,
                                                      const int* __restrict__ ei,
                                                      float* __restrict__ out) {
    const int t = blockIdx.x * 256 + threadIdx.x;
    const int e = t >> 4;
    if (e >= N_EDGES) return;
    const int c = (t & 15) * 4;
    const int src = ei[e];
    const int dst = ei[N_EDGES + e];
    const float4 v = *(const float4*)(xw + (size_t)src * HID_CH + c);
    float* o = out + (size_t)dst * HID_CH + c;
    atomicAdd(o + 0, v.x);
    atomicAdd(o + 1, v.y);
    atomicAdd(o + 2, v.z);
    atomicAdd(o + 3, v.w);
}

// ---------------------------------------------------------------------------
// Kernel 3: out = prelu(out + bias). Per-channel bias/alpha, channel = i & 63.
// ---------------------------------------------------------------------------
__global__ __launch_bounds__(256) void epilogue_kernel(float* __restrict__ out,
                                                       const float* __restrict__ bias,
                                                       const float* __restrict__ prelu_a) {
    const int i = blockIdx.x * 256 + threadIdx.x;
    if (i < N_NODES * HID_CH) {
        const int c = i & 63;
        const float v = out[i] + bias[c];
        out[i] = v > 0.f ? v : prelu_a[c] * v;
    }
}

extern "C" void kernel_launch(void* const* d_in, const int* in_sizes, int n_in,
                              void* d_out, int out_size, void* d_ws, size_t ws_size,
                              hipStream_t stream) {
    const float* x       = (const float*)d_in[0];
    const int*   ei      = (const int*)d_in[1];   // [2, E], row-major: src then dst
    const float* W       = (const float*)d_in[2];
    const float* bias    = (const float*)d_in[3];
    const float* prelu_a = (const float*)d_in[4];
    float* out = (float*)d_out;
    float* xw  = (float*)d_ws;                    // N_NODES * HID_CH fp32 = 12.8 MB

    // xw = x @ W
    gemm_kernel<<<(N_NODES + 3) / 4, 256, 0, stream>>>(x, W, xw);

    // out = 0
    hipMemsetAsync(out, 0, (size_t)N_NODES * HID_CH * sizeof(float), stream);

    // out[dst] += xw[src]
    const int scatter_threads = N_EDGES * 16;
    scatter_kernel<<<(scatter_threads + 255) / 256, 256, 0, stream>>>(xw, ei, out);

    // out = prelu(out + bias)
    epilogue_kernel<<<(N_NODES * HID_CH + 255) / 256, 256, 0, stream>>>(out, bias, prelu_a);
}

// Round 2
// 442.262 us; speedup vs baseline: 2.1885x; 2.1885x over previous
//
#include <hip/hip_runtime.h>

#define N_NODES 50000
#define IN_CH   256
#define HID_CH  64
#define N_EDGES 800000

// ---------------------------------------------------------------------------
// Kernel 1: xw = x @ W, tiled. Block tile 128 rows x 64 ch, thread tile 8x4.
// LDS: x-tile [128][KC+4] (pad 4 keeps b128 alignment) + W-chunk [KC][64].
// Per k4: 12 ds_read_b128 vs 128 v_fma -> VALU-bound.
// ---------------------------------------------------------------------------
#define GR 128   // rows per block
#define KC 64    // k-chunk
#define XS_LD (KC + 4)

__global__ __launch_bounds__(256) void gemm_kernel(const float* __restrict__ x,
                                                   const float* __restrict__ W,
                                                   float* __restrict__ xw) {
    __shared__ float xs[GR * XS_LD];    // 34816 B
    __shared__ float Ws[KC * HID_CH];   // 16384 B
    const int tid = threadIdx.x;
    const int rg = tid >> 4;            // 0..15 row group
    const int cg = tid & 15;            // 0..15 col group
    const int r0 = rg * 8;
    const int c0 = cg * 4;
    const int rowbase = blockIdx.x * GR;

    float acc[8][4];
    #pragma unroll
    for (int j = 0; j < 8; ++j)
        #pragma unroll
        for (int t = 0; t < 4; ++t) acc[j][t] = 0.f;

    for (int kc0 = 0; kc0 < IN_CH; kc0 += KC) {
        // stage W chunk (contiguous 16 KB)
        {
            const float4* src = (const float4*)(W + kc0 * HID_CH);
            float4* dst = (float4*)Ws;
            #pragma unroll
            for (int i = 0; i < 4; ++i) dst[tid + 256 * i] = src[tid + 256 * i];
        }
        // stage x tile [128 rows][KC], row-major, coalesced 256 B per 16 lanes
        {
            const int kj = (tid & 15) * 4;
            const int rr = tid >> 4;
            #pragma unroll
            for (int p = 0; p < 8; ++p) {
                const int rloc = p * 16 + rr;
                int row = rowbase + rloc;
                int rl = min(row, N_NODES - 1);
                float4 v = *(const float4*)(x + (size_t)rl * IN_CH + kc0 + kj);
                *(float4*)(&xs[rloc * XS_LD + kj]) = v;
            }
        }
        __syncthreads();

        #pragma unroll
        for (int k4 = 0; k4 < KC; k4 += 4) {
            float4 wv[4];
            #pragma unroll
            for (int kk = 0; kk < 4; ++kk)
                wv[kk] = *(const float4*)(&Ws[(k4 + kk) * HID_CH + c0]);
            #pragma unroll
            for (int j = 0; j < 8; ++j) {
                const float4 xv = *(const float4*)(&xs[(r0 + j) * XS_LD + k4]);
                acc[j][0] += xv.x * wv[0].x + xv.y * wv[1].x + xv.z * wv[2].x + xv.w * wv[3].x;
                acc[j][1] += xv.x * wv[0].y + xv.y * wv[1].y + xv.z * wv[2].y + xv.w * wv[3].y;
                acc[j][2] += xv.x * wv[0].z + xv.y * wv[1].z + xv.z * wv[2].z + xv.w * wv[3].z;
                acc[j][3] += xv.x * wv[0].w + xv.y * wv[1].w + xv.z * wv[2].w + xv.w * wv[3].w;
            }
        }
        __syncthreads();
    }

    #pragma unroll
    for (int j = 0; j < 8; ++j) {
        const int row = rowbase + r0 + j;
        if (row < N_NODES) {
            float4 v = make_float4(acc[j][0], acc[j][1], acc[j][2], acc[j][3]);
            *(float4*)(xw + (size_t)row * HID_CH + c0) = v;
        }
    }
}

// ---------------------------------------------------------------------------
// Kernel 2: degree histogram over dst. cur[] doubles as deg[] (zeroed first).
// ---------------------------------------------------------------------------
__global__ __launch_bounds__(256) void hist_kernel(const int* __restrict__ ei,
                                                   int* __restrict__ deg) {
    const int e = blockIdx.x * 256 + threadIdx.x;
    if (e < N_EDGES) atomicAdd(&deg[ei[N_EDGES + e]], 1);
}

// ---------------------------------------------------------------------------
// Kernel 3: single-block exclusive prefix scan over 50000 degrees.
// Writes offsets[] (persistent) and rewrites deg->cur[] (start cursors).
// ---------------------------------------------------------------------------
#define SCAN_T 1024
#define CHUNK  49   // 49*1024 = 50176 >= N_NODES

__global__ __launch_bounds__(SCAN_T) void scan_kernel(int* __restrict__ deg_cur,
                                                      int* __restrict__ offsets) {
    __shared__ int part[SCAN_T];
    const int t = threadIdx.x;
    const int base = t * CHUNK;
    int s = 0;
    for (int i = 0; i < CHUNK; ++i) {
        const int idx = base + i;
        if (idx < N_NODES) s += deg_cur[idx];
    }
    part[t] = s;
    __syncthreads();
    // Hillis-Steele inclusive scan
    for (int off = 1; off < SCAN_T; off <<= 1) {
        const int v = part[t];
        const int add = (t >= off) ? part[t - off] : 0;
        __syncthreads();
        part[t] = v + add;
        __syncthreads();
    }
    int run = (t > 0) ? part[t - 1] : 0;
    for (int i = 0; i < CHUNK; ++i) {
        const int idx = base + i;
        if (idx < N_NODES) {
            const int v = deg_cur[idx];
            offsets[idx] = run;
            deg_cur[idx] = run;   // cursor for scatter
            run += v;
        }
    }
    if (t == 0) offsets[N_NODES] = N_EDGES;
}

// ---------------------------------------------------------------------------
// Kernel 4: scatter edge srcs into dst-sorted order via cursor bump.
// ---------------------------------------------------------------------------
__global__ __launch_bounds__(256) void scatter_sort_kernel(const int* __restrict__ ei,
                                                           int* __restrict__ cur,
                                                           int* __restrict__ sorted_src) {
    const int e = blockIdx.x * 256 + threadIdx.x;
    if (e < N_EDGES) {
        const int src = ei[e];
        const int dst = ei[N_EDGES + e];
        const int pos = atomicAdd(&cur[dst], 1);
        sorted_src[pos] = src;
    }
}

// ---------------------------------------------------------------------------
// Kernel 5: segment-reduce. One wave per node, lane = channel. No atomics.
// Fuses bias + PReLU; writes every output element exactly once.
// ---------------------------------------------------------------------------
__global__ __launch_bounds__(256) void aggregate_kernel(const float* __restrict__ xw,
                                                        const int* __restrict__ offsets,
                                                        const int* __restrict__ sorted_src,
                                                        const float* __restrict__ bias,
                                                        const float* __restrict__ prelu_a,
                                                        float* __restrict__ out) {
    const int wave = threadIdx.x >> 6;
    const int lane = threadIdx.x & 63;
    const int n = blockIdx.x * 4 + wave;
    if (n >= N_NODES) return;
    const int beg = offsets[n];
    const int end = offsets[n + 1];
    float a0 = 0.f, a1 = 0.f;
    int i = beg;
    for (; i + 1 < end; i += 2) {
        const int s0 = sorted_src[i];
        const int s1 = sorted_src[i + 1];
        a0 += xw[(size_t)s0 * HID_CH + lane];
        a1 += xw[(size_t)s1 * HID_CH + lane];
    }
    if (i < end) a0 += xw[(size_t)sorted_src[i] * HID_CH + lane];
    const float v = a0 + a1 + bias[lane];
    out[(size_t)n * HID_CH + lane] = v > 0.f ? v : prelu_a[lane] * v;
}

extern "C" void kernel_launch(void* const* d_in, const int* in_sizes, int n_in,
                              void* d_out, int out_size, void* d_ws, size_t ws_size,
                              hipStream_t stream) {
    const float* x       = (const float*)d_in[0];
    const int*   ei      = (const int*)d_in[1];   // [2, E]: src row then dst row
    const float* W       = (const float*)d_in[2];
    const float* bias    = (const float*)d_in[3];
    const float* prelu_a = (const float*)d_in[4];
    float* out = (float*)d_out;

    // workspace layout (all 16B-aligned offsets)
    char* w = (char*)d_ws;
    float* xw      = (float*)(w);              // 12,800,000 B
    int*   cur     = (int*)(w + 12800000);     //    200,000 B (deg -> cursor)
    int*   offsets = (int*)(w + 13000192);     //    200,004 B
    int*   sorted  = (int*)(w + 13200384);     //  3,200,000 B
    // total ~16.4 MB

    // 1) xw = x @ W
    gemm_kernel<<<(N_NODES + GR - 1) / GR, 256, 0, stream>>>(x, W, xw);

    // 2) deg = 0; histogram over dst
    hipMemsetAsync(cur, 0, N_NODES * sizeof(int), stream);
    hist_kernel<<<(N_EDGES + 255) / 256, 256, 0, stream>>>(ei, cur);

    // 3) exclusive scan -> offsets, cursors
    scan_kernel<<<1, SCAN_T, 0, stream>>>(cur, offsets);

    // 4) dst-sort edge srcs
    scatter_sort_kernel<<<(N_EDGES + 255) / 256, 256, 0, stream>>>(ei, cur, sorted);

    // 5) segment-reduce + bias + PReLU
    aggregate_kernel<<<(N_NODES + 3) / 4, 256, 0, stream>>>(xw, offsets, sorted, bias, prelu_a, out);
}

// Round 3
// 321.437 us; speedup vs baseline: 3.0111x; 1.3759x over previous
//
#include <hip/hip_runtime.h>

#define N_NODES 50000
#define IN_CH   256
#define HID_CH  64
#define N_EDGES 800000

// ---------------------------------------------------------------------------
// Kernel 1: xw = x @ W, tiled. Block tile 128 rows x 64 ch, thread tile 8x4.
// ---------------------------------------------------------------------------
#define GR 128   // rows per block
#define KC 64    // k-chunk
#define XS_LD (KC + 4)

__global__ __launch_bounds__(256) void gemm_kernel(const float* __restrict__ x,
                                                   const float* __restrict__ W,
                                                   float* __restrict__ xw) {
    __shared__ float xs[GR * XS_LD];    // 34816 B
    __shared__ float Ws[KC * HID_CH];   // 16384 B
    const int tid = threadIdx.x;
    const int rg = tid >> 4;            // 0..15 row group
    const int cg = tid & 15;            // 0..15 col group
    const int r0 = rg * 8;
    const int c0 = cg * 4;
    const int rowbase = blockIdx.x * GR;

    float acc[8][4];
    #pragma unroll
    for (int j = 0; j < 8; ++j)
        #pragma unroll
        for (int t = 0; t < 4; ++t) acc[j][t] = 0.f;

    for (int kc0 = 0; kc0 < IN_CH; kc0 += KC) {
        {
            const float4* src = (const float4*)(W + kc0 * HID_CH);
            float4* dst = (float4*)Ws;
            #pragma unroll
            for (int i = 0; i < 4; ++i) dst[tid + 256 * i] = src[tid + 256 * i];
        }
        {
            const int kj = (tid & 15) * 4;
            const int rr = tid >> 4;
            #pragma unroll
            for (int p = 0; p < 8; ++p) {
                const int rloc = p * 16 + rr;
                int row = rowbase + rloc;
                int rl = min(row, N_NODES - 1);
                float4 v = *(const float4*)(x + (size_t)rl * IN_CH + kc0 + kj);
                *(float4*)(&xs[rloc * XS_LD + kj]) = v;
            }
        }
        __syncthreads();

        #pragma unroll
        for (int k4 = 0; k4 < KC; k4 += 4) {
            float4 wv[4];
            #pragma unroll
            for (int kk = 0; kk < 4; ++kk)
                wv[kk] = *(const float4*)(&Ws[(k4 + kk) * HID_CH + c0]);
            #pragma unroll
            for (int j = 0; j < 8; ++j) {
                const float4 xv = *(const float4*)(&xs[(r0 + j) * XS_LD + k4]);
                acc[j][0] += xv.x * wv[0].x + xv.y * wv[1].x + xv.z * wv[2].x + xv.w * wv[3].x;
                acc[j][1] += xv.x * wv[0].y + xv.y * wv[1].y + xv.z * wv[2].y + xv.w * wv[3].y;
                acc[j][2] += xv.x * wv[0].z + xv.y * wv[1].z + xv.z * wv[2].z + xv.w * wv[3].z;
                acc[j][3] += xv.x * wv[0].w + xv.y * wv[1].w + xv.z * wv[2].w + xv.w * wv[3].w;
            }
        }
        __syncthreads();
    }

    #pragma unroll
    for (int j = 0; j < 8; ++j) {
        const int row = rowbase + r0 + j;
        if (row < N_NODES) {
            float4 v = make_float4(acc[j][0], acc[j][1], acc[j][2], acc[j][3]);
            *(float4*)(xw + (size_t)row * HID_CH + c0) = v;
        }
    }
}

// ---------------------------------------------------------------------------
// Kernel 2: degree histogram over dst.
// ---------------------------------------------------------------------------
__global__ __launch_bounds__(256) void hist_kernel(const int* __restrict__ ei,
                                                   int* __restrict__ deg) {
    const int e = blockIdx.x * 256 + threadIdx.x;
    if (e < N_EDGES) atomicAdd(&deg[ei[N_EDGES + e]], 1);
}

// ---------------------------------------------------------------------------
// Kernels 3a/3b/3c: multi-block exclusive scan of deg -> offsets + cursors.
// 196 blocks x 256 = 50176 >= N_NODES.
// ---------------------------------------------------------------------------
#define SCAN_B 196

__global__ __launch_bounds__(256) void scan_partial_kernel(const int* __restrict__ deg,
                                                           int* __restrict__ partials) {
    __shared__ int s[256];
    const int t = threadIdx.x;
    const int idx = blockIdx.x * 256 + t;
    s[t] = (idx < N_NODES) ? deg[idx] : 0;
    __syncthreads();
    #pragma unroll
    for (int off = 128; off > 0; off >>= 1) {
        if (t < off) s[t] += s[t + off];
        __syncthreads();
    }
    if (t == 0) partials[blockIdx.x] = s[0];
}

__global__ __launch_bounds__(256) void scan_partials_kernel(int* __restrict__ partials) {
    __shared__ int s[256];
    const int t = threadIdx.x;
    const int v = (t < SCAN_B) ? partials[t] : 0;
    s[t] = v;
    __syncthreads();
    #pragma unroll
    for (int off = 1; off < 256; off <<= 1) {
        const int a = s[t];
        const int add = (t >= off) ? s[t - off] : 0;
        __syncthreads();
        s[t] = a + add;
        __syncthreads();
    }
    if (t < SCAN_B) partials[t] = s[t] - v;   // exclusive
}

__global__ __launch_bounds__(256) void scan_final_kernel(int* __restrict__ deg_cur,
                                                         int* __restrict__ offsets,
                                                         const int* __restrict__ partials) {
    __shared__ int s[256];
    const int t = threadIdx.x;
    const int idx = blockIdx.x * 256 + t;
    const int v = (idx < N_NODES) ? deg_cur[idx] : 0;
    s[t] = v;
    __syncthreads();
    #pragma unroll
    for (int off = 1; off < 256; off <<= 1) {
        const int a = s[t];
        const int add = (t >= off) ? s[t - off] : 0;
        __syncthreads();
        s[t] = a + add;
        __syncthreads();
    }
    const int excl = s[t] - v + partials[blockIdx.x];
    if (idx < N_NODES) {
        offsets[idx] = excl;
        deg_cur[idx] = excl;   // cursor for scatter
    }
    if (idx == 0) offsets[N_NODES] = N_EDGES;
}

// ---------------------------------------------------------------------------
// Kernel 4: scatter edge srcs into dst-sorted order via cursor bump.
// ---------------------------------------------------------------------------
__global__ __launch_bounds__(256) void scatter_sort_kernel(const int* __restrict__ ei,
                                                           int* __restrict__ cur,
                                                           int* __restrict__ sorted_src) {
    const int e = blockIdx.x * 256 + threadIdx.x;
    if (e < N_EDGES) {
        const int src = ei[e];
        const int dst = ei[N_EDGES + e];
        const int pos = atomicAdd(&cur[dst], 1);
        sorted_src[pos] = src;
    }
}

// ---------------------------------------------------------------------------
// Kernel 5: segment-reduce. One wave per node, lane = channel. No atomics.
// Fuses bias + PReLU.
// ---------------------------------------------------------------------------
__global__ __launch_bounds__(256) void aggregate_kernel(const float* __restrict__ xw,
                                                        const int* __restrict__ offsets,
                                                        const int* __restrict__ sorted_src,
                                                        const float* __restrict__ bias,
                                                        const float* __restrict__ prelu_a,
                                                        float* __restrict__ out) {
    const int wave = threadIdx.x >> 6;
    const int lane = threadIdx.x & 63;
    const int n = blockIdx.x * 4 + wave;
    if (n >= N_NODES) return;
    const int beg = offsets[n];
    const int end = offsets[n + 1];
    float a0 = 0.f, a1 = 0.f;
    int i = beg;
    for (; i + 1 < end; i += 2) {
        const int s0 = sorted_src[i];
        const int s1 = sorted_src[i + 1];
        a0 += xw[(size_t)s0 * HID_CH + lane];
        a1 += xw[(size_t)s1 * HID_CH + lane];
    }
    if (i < end) a0 += xw[(size_t)sorted_src[i] * HID_CH + lane];
    const float v = a0 + a1 + bias[lane];
    out[(size_t)n * HID_CH + lane] = v > 0.f ? v : prelu_a[lane] * v;
}

extern "C" void kernel_launch(void* const* d_in, const int* in_sizes, int n_in,
                              void* d_out, int out_size, void* d_ws, size_t ws_size,
                              hipStream_t stream) {
    const float* x       = (const float*)d_in[0];
    const int*   ei      = (const int*)d_in[1];   // [2, E]: src row then dst row
    const float* W       = (const float*)d_in[2];
    const float* bias    = (const float*)d_in[3];
    const float* prelu_a = (const float*)d_in[4];
    float* out = (float*)d_out;

    // workspace layout
    char* w = (char*)d_ws;
    float* xw       = (float*)(w);              // 12,800,000 B
    int*   cur      = (int*)(w + 12800000);     //    200,000 B (deg -> cursor)
    int*   offsets  = (int*)(w + 13000192);     //    200,004 B
    int*   sorted   = (int*)(w + 13200384);     //  3,200,000 B
    int*   partials = (int*)(w + 16400384);     //        784 B

    // 1) xw = x @ W
    gemm_kernel<<<(N_NODES + GR - 1) / GR, 256, 0, stream>>>(x, W, xw);

    // 2) deg = 0; histogram over dst
    hipMemsetAsync(cur, 0, N_NODES * sizeof(int), stream);
    hist_kernel<<<(N_EDGES + 255) / 256, 256, 0, stream>>>(ei, cur);

    // 3) multi-block exclusive scan -> offsets, cursors
    scan_partial_kernel<<<SCAN_B, 256, 0, stream>>>(cur, partials);
    scan_partials_kernel<<<1, 256, 0, stream>>>(partials);
    scan_final_kernel<<<SCAN_B, 256, 0, stream>>>(cur, offsets, partials);

    // 4) dst-sort edge srcs
    scatter_sort_kernel<<<(N_EDGES + 255) / 256, 256, 0, stream>>>(ei, cur, sorted);

    // 5) segment-reduce + bias + PReLU
    aggregate_kernel<<<(N_NODES + 3) / 4, 256, 0, stream>>>(xw, offsets, sorted, bias, prelu_a, out);
}

// Round 4
// 264.926 us; speedup vs baseline: 3.6534x; 1.2133x over previous
//
#include <hip/hip_runtime.h>

#define N_NODES 50000
#define IN_CH   256
#define HID_CH  64
#define N_EDGES 800000

// ---------------------------------------------------------------------------
// Kernel 1: xw = x @ W, tiled. Block tile 64 rows x 64 ch, thread tile 4x4.
// Grid 782 blocks (~3/CU); LDS 33.8 KB; target VGPR <= 128 for 4 waves/SIMD.
// ---------------------------------------------------------------------------
#define GR 64    // rows per block
#define KC 64    // k-chunk
#define XS_LD (KC + 4)

__global__ __launch_bounds__(256) void gemm_kernel(const float* __restrict__ x,
                                                   const float* __restrict__ W,
                                                   float* __restrict__ xw) {
    __shared__ float xs[GR * XS_LD];    // 17408 B
    __shared__ float Ws[KC * HID_CH];   // 16384 B
    const int tid = threadIdx.x;
    const int rg = tid >> 4;            // 0..15 row group (4 rows each)
    const int cg = tid & 15;            // 0..15 col group (4 cols each)
    const int r0 = rg * 4;
    const int c0 = cg * 4;
    const int rowbase = blockIdx.x * GR;

    float acc[4][4];
    #pragma unroll
    for (int j = 0; j < 4; ++j)
        #pragma unroll
        for (int t = 0; t < 4; ++t) acc[j][t] = 0.f;

    for (int kc0 = 0; kc0 < IN_CH; kc0 += KC) {
        // stage W chunk: 16 KB contiguous, 4 float4 per thread
        {
            const float4* src = (const float4*)(W + kc0 * HID_CH);
            float4* dst = (float4*)Ws;
            #pragma unroll
            for (int i = 0; i < 4; ++i) dst[tid + 256 * i] = src[tid + 256 * i];
        }
        // stage x tile: 64 rows x 64 k = 1024 float4, 4 per thread, coalesced
        {
            #pragma unroll
            for (int p = 0; p < 4; ++p) {
                const int idx = tid + 256 * p;        // float4 index
                const int rloc = idx >> 4;            // row in tile
                const int kj = (idx & 15) * 4;        // k within chunk
                const int row = rowbase + rloc;
                const int rl = row < N_NODES ? row : N_NODES - 1;
                float4 v = *(const float4*)(x + (size_t)rl * IN_CH + kc0 + kj);
                *(float4*)(&xs[rloc * XS_LD + kj]) = v;
            }
        }
        __syncthreads();

        #pragma unroll
        for (int k4 = 0; k4 < KC; k4 += 4) {
            float4 wv[4];
            #pragma unroll
            for (int kk = 0; kk < 4; ++kk)
                wv[kk] = *(const float4*)(&Ws[(k4 + kk) * HID_CH + c0]);
            #pragma unroll
            for (int j = 0; j < 4; ++j) {
                const float4 xv = *(const float4*)(&xs[(r0 + j) * XS_LD + k4]);
                acc[j][0] += xv.x * wv[0].x + xv.y * wv[1].x + xv.z * wv[2].x + xv.w * wv[3].x;
                acc[j][1] += xv.x * wv[0].y + xv.y * wv[1].y + xv.z * wv[2].y + xv.w * wv[3].y;
                acc[j][2] += xv.x * wv[0].z + xv.y * wv[1].z + xv.z * wv[2].z + xv.w * wv[3].z;
                acc[j][3] += xv.x * wv[0].w + xv.y * wv[1].w + xv.z * wv[2].w + xv.w * wv[3].w;
            }
        }
        __syncthreads();
    }

    #pragma unroll
    for (int j = 0; j < 4; ++j) {
        const int row = rowbase + r0 + j;
        if (row < N_NODES) {
            float4 v = make_float4(acc[j][0], acc[j][1], acc[j][2], acc[j][3]);
            *(float4*)(xw + (size_t)row * HID_CH + c0) = v;
        }
    }
}

// ---------------------------------------------------------------------------
// Kernel 2: degree histogram over dst.
// ---------------------------------------------------------------------------
__global__ __launch_bounds__(256) void hist_kernel(const int* __restrict__ ei,
                                                   int* __restrict__ deg) {
    const int e = blockIdx.x * 256 + threadIdx.x;
    if (e < N_EDGES) atomicAdd(&deg[ei[N_EDGES + e]], 1);
}

// ---------------------------------------------------------------------------
// Kernels 3a/3b/3c: multi-block exclusive scan of deg -> offsets + cursors.
// ---------------------------------------------------------------------------
#define SCAN_B 196

__global__ __launch_bounds__(256) void scan_partial_kernel(const int* __restrict__ deg,
                                                           int* __restrict__ partials) {
    __shared__ int s[256];
    const int t = threadIdx.x;
    const int idx = blockIdx.x * 256 + t;
    s[t] = (idx < N_NODES) ? deg[idx] : 0;
    __syncthreads();
    #pragma unroll
    for (int off = 128; off > 0; off >>= 1) {
        if (t < off) s[t] += s[t + off];
        __syncthreads();
    }
    if (t == 0) partials[blockIdx.x] = s[0];
}

__global__ __launch_bounds__(256) void scan_partials_kernel(int* __restrict__ partials) {
    __shared__ int s[256];
    const int t = threadIdx.x;
    const int v = (t < SCAN_B) ? partials[t] : 0;
    s[t] = v;
    __syncthreads();
    #pragma unroll
    for (int off = 1; off < 256; off <<= 1) {
        const int a = s[t];
        const int add = (t >= off) ? s[t - off] : 0;
        __syncthreads();
        s[t] = a + add;
        __syncthreads();
    }
    if (t < SCAN_B) partials[t] = s[t] - v;   // exclusive
}

__global__ __launch_bounds__(256) void scan_final_kernel(int* __restrict__ deg_cur,
                                                         int* __restrict__ offsets,
                                                         const int* __restrict__ partials) {
    __shared__ int s[256];
    const int t = threadIdx.x;
    const int idx = blockIdx.x * 256 + t;
    const int v = (idx < N_NODES) ? deg_cur[idx] : 0;
    s[t] = v;
    __syncthreads();
    #pragma unroll
    for (int off = 1; off < 256; off <<= 1) {
        const int a = s[t];
        const int add = (t >= off) ? s[t - off] : 0;
        __syncthreads();
        s[t] = a + add;
        __syncthreads();
    }
    const int excl = s[t] - v + partials[blockIdx.x];
    if (idx < N_NODES) {
        offsets[idx] = excl;
        deg_cur[idx] = excl;   // cursor for scatter
    }
    if (idx == 0) offsets[N_NODES] = N_EDGES;
}

// ---------------------------------------------------------------------------
// Kernel 4: scatter edge srcs into dst-sorted order via cursor bump.
// ---------------------------------------------------------------------------
__global__ __launch_bounds__(256) void scatter_sort_kernel(const int* __restrict__ ei,
                                                           int* __restrict__ cur,
                                                           int* __restrict__ sorted_src) {
    const int e = blockIdx.x * 256 + threadIdx.x;
    if (e < N_EDGES) {
        const int src = ei[e];
        const int dst = ei[N_EDGES + e];
        const int pos = atomicAdd(&cur[dst], 1);
        sorted_src[pos] = src;
    }
}

// ---------------------------------------------------------------------------
// Kernel 5: segment-reduce, vectorized. One wave per node; slot = lane>>4
// processes every 4th edge; lane&15 covers 64 channels as float4 (16 B/lane).
// Cross-slot reduce via shfl_xor. Fuses bias + PReLU. No atomics.
// ---------------------------------------------------------------------------
__global__ __launch_bounds__(256) void aggregate_kernel(const float* __restrict__ xw,
                                                        const int* __restrict__ offsets,
                                                        const int* __restrict__ sorted_src,
                                                        const float* __restrict__ bias,
                                                        const float* __restrict__ prelu_a,
                                                        float* __restrict__ out) {
    const int wave = threadIdx.x >> 6;
    const int lane = threadIdx.x & 63;
    const int n = blockIdx.x * 4 + wave;
    if (n >= N_NODES) return;
    const int slot = lane >> 4;          // 0..3: which edge in the group of 4
    const int c0 = (lane & 15) * 4;      // channel group
    const int beg = offsets[n];
    const int end = offsets[n + 1];

    float4 acc = make_float4(0.f, 0.f, 0.f, 0.f);
    for (int i = beg + slot; i < end; i += 4) {
        const int s = sorted_src[i];
        const float4 v = *(const float4*)(xw + (size_t)s * HID_CH + c0);
        acc.x += v.x; acc.y += v.y; acc.z += v.z; acc.w += v.w;
    }
    // reduce the 4 slots: lanes {l, l^16, l^32, l^48}
    acc.x += __shfl_xor(acc.x, 16, 64); acc.y += __shfl_xor(acc.y, 16, 64);
    acc.z += __shfl_xor(acc.z, 16, 64); acc.w += __shfl_xor(acc.w, 16, 64);
    acc.x += __shfl_xor(acc.x, 32, 64); acc.y += __shfl_xor(acc.y, 32, 64);
    acc.z += __shfl_xor(acc.z, 32, 64); acc.w += __shfl_xor(acc.w, 32, 64);

    if (slot == 0) {
        const float4 b = *(const float4*)(bias + c0);
        const float4 a = *(const float4*)(prelu_a + c0);
        float4 r;
        r.x = acc.x + b.x; r.x = r.x > 0.f ? r.x : a.x * r.x;
        r.y = acc.y + b.y; r.y = r.y > 0.f ? r.y : a.y * r.y;
        r.z = acc.z + b.z; r.z = r.z > 0.f ? r.z : a.z * r.z;
        r.w = acc.w + b.w; r.w = r.w > 0.f ? r.w : a.w * r.w;
        *(float4*)(out + (size_t)n * HID_CH + c0) = r;
    }
}

extern "C" void kernel_launch(void* const* d_in, const int* in_sizes, int n_in,
                              void* d_out, int out_size, void* d_ws, size_t ws_size,
                              hipStream_t stream) {
    const float* x       = (const float*)d_in[0];
    const int*   ei      = (const int*)d_in[1];   // [2, E]: src row then dst row
    const float* W       = (const float*)d_in[2];
    const float* bias    = (const float*)d_in[3];
    const float* prelu_a = (const float*)d_in[4];
    float* out = (float*)d_out;

    // workspace layout
    char* w = (char*)d_ws;
    float* xw       = (float*)(w);              // 12,800,000 B
    int*   cur      = (int*)(w + 12800000);     //    200,000 B (deg -> cursor)
    int*   offsets  = (int*)(w + 13000192);     //    200,004 B
    int*   sorted   = (int*)(w + 13200384);     //  3,200,000 B
    int*   partials = (int*)(w + 16400384);     //        784 B

    // 1) xw = x @ W
    gemm_kernel<<<(N_NODES + GR - 1) / GR, 256, 0, stream>>>(x, W, xw);

    // 2) deg = 0; histogram over dst
    hipMemsetAsync(cur, 0, N_NODES * sizeof(int), stream);
    hist_kernel<<<(N_EDGES + 255) / 256, 256, 0, stream>>>(ei, cur);

    // 3) multi-block exclusive scan -> offsets, cursors
    scan_partial_kernel<<<SCAN_B, 256, 0, stream>>>(cur, partials);
    scan_partials_kernel<<<1, 256, 0, stream>>>(partials);
    scan_final_kernel<<<SCAN_B, 256, 0, stream>>>(cur, offsets, partials);

    // 4) dst-sort edge srcs
    scatter_sort_kernel<<<(N_EDGES + 255) / 256, 256, 0, stream>>>(ei, cur, sorted);

    // 5) segment-reduce + bias + PReLU
    aggregate_kernel<<<(N_NODES + 3) / 4, 256, 0, stream>>>(xw, offsets, sorted, bias, prelu_a, out);
}

// Round 5
// 227.165 us; speedup vs baseline: 4.2607x; 1.1662x over previous
//
#include <hip/hip_runtime.h>

#define N_NODES 50000
#define IN_CH   256
#define HID_CH  64
#define N_EDGES 800000

typedef __attribute__((ext_vector_type(8))) short short8;
typedef __attribute__((ext_vector_type(4))) float f32x4;

static __device__ __forceinline__ unsigned short f2bf(float f) {
    unsigned int u = __float_as_uint(f);
    u += 0x7FFF + ((u >> 16) & 1);   // RNE
    return (unsigned short)(u >> 16);
}
static __device__ __forceinline__ float bf2f(unsigned short h) {
    return __uint_as_float(((unsigned int)h) << 16);
}

// ---------------------------------------------------------------------------
// Kernel 0: precompute W B-fragments (bf16), slot = (kstep, ntile, lane).
// wfrag[((ks*4+nt)*64 + lane)*8 + j] = bf16(W[(ks*32 + (lane>>4)*8 + j)*64 + nt*16 + (lane&15)])
// 2048 slots x 16 B = 32 KB, L1/L2-resident for the GEMM.
// ---------------------------------------------------------------------------
__global__ __launch_bounds__(256) void wfrag_kernel(const float* __restrict__ W,
                                                    unsigned short* __restrict__ wfrag) {
    const int idx = blockIdx.x * 256 + threadIdx.x;
    if (idx >= 2048) return;
    const int ks = idx >> 8;
    const int nt = (idx >> 6) & 3;
    const int l  = idx & 63;
    const int q = l >> 4, m = l & 15;
    const int n = nt * 16 + m;
    const int k0 = ks * 32 + q * 8;
    short8 v;
    #pragma unroll
    for (int j = 0; j < 8; ++j) v[j] = (short)f2bf(W[(k0 + j) * HID_CH + n]);
    ((short8*)wfrag)[idx] = v;
}

// ---------------------------------------------------------------------------
// Kernel 1: xw = bf16(x @ W) via MFMA 16x16x32 bf16. No LDS, no barriers.
// Block = 4 waves, each wave owns a 16-row x 64-col tile (4 n-tiles).
// A-frag: lane l holds x[row0 + (l&15)][ks*32 + (l>>4)*8 + 0..7].
// ---------------------------------------------------------------------------
__global__ __launch_bounds__(256) void gemm_kernel(const float* __restrict__ x,
                                                   const unsigned short* __restrict__ wfrag,
                                                   unsigned short* __restrict__ xwb) {
    const int wave = threadIdx.x >> 6;
    const int lane = threadIdx.x & 63;
    const int q = lane >> 4, m = lane & 15;
    const int row0 = blockIdx.x * 64 + wave * 16;
    const int arow = row0 + m;
    const int arl = arow < N_NODES ? arow : N_NODES - 1;
    const float* xr = x + (size_t)arl * IN_CH + q * 8;
    const short8* wf = (const short8*)wfrag;

    f32x4 acc0 = {0.f,0.f,0.f,0.f}, acc1 = acc0, acc2 = acc0, acc3 = acc0;

    #pragma unroll
    for (int ks = 0; ks < 8; ++ks) {
        const float4 a0 = *(const float4*)(xr + ks * 32);
        const float4 a1 = *(const float4*)(xr + ks * 32 + 4);
        short8 af;
        af[0] = (short)f2bf(a0.x); af[1] = (short)f2bf(a0.y);
        af[2] = (short)f2bf(a0.z); af[3] = (short)f2bf(a0.w);
        af[4] = (short)f2bf(a1.x); af[5] = (short)f2bf(a1.y);
        af[6] = (short)f2bf(a1.z); af[7] = (short)f2bf(a1.w);
        const short8 b0 = wf[(ks * 4 + 0) * 64 + lane];
        const short8 b1 = wf[(ks * 4 + 1) * 64 + lane];
        const short8 b2 = wf[(ks * 4 + 2) * 64 + lane];
        const short8 b3 = wf[(ks * 4 + 3) * 64 + lane];
        acc0 = __builtin_amdgcn_mfma_f32_16x16x32_bf16(af, b0, acc0, 0, 0, 0);
        acc1 = __builtin_amdgcn_mfma_f32_16x16x32_bf16(af, b1, acc1, 0, 0, 0);
        acc2 = __builtin_amdgcn_mfma_f32_16x16x32_bf16(af, b2, acc2, 0, 0, 0);
        acc3 = __builtin_amdgcn_mfma_f32_16x16x32_bf16(af, b3, acc3, 0, 0, 0);
    }

    // C/D: row = row0 + q*4 + r, col = nt*16 + m
    #pragma unroll
    for (int r = 0; r < 4; ++r) {
        const int row = row0 + q * 4 + r;
        if (row < N_NODES) {
            unsigned short* o = xwb + (size_t)row * HID_CH + m;
            o[0]  = f2bf(acc0[r]);
            o[16] = f2bf(acc1[r]);
            o[32] = f2bf(acc2[r]);
            o[48] = f2bf(acc3[r]);
        }
    }
}

// ---------------------------------------------------------------------------
// Kernel 2: degree histogram over dst.
// ---------------------------------------------------------------------------
__global__ __launch_bounds__(256) void hist_kernel(const int* __restrict__ ei,
                                                   int* __restrict__ deg) {
    const int e = blockIdx.x * 256 + threadIdx.x;
    if (e < N_EDGES) atomicAdd(&deg[ei[N_EDGES + e]], 1);
}

// ---------------------------------------------------------------------------
// Kernels 3a/3b/3c: multi-block exclusive scan of deg -> offsets + cursors.
// ---------------------------------------------------------------------------
#define SCAN_B 196

__global__ __launch_bounds__(256) void scan_partial_kernel(const int* __restrict__ deg,
                                                           int* __restrict__ partials) {
    __shared__ int s[256];
    const int t = threadIdx.x;
    const int idx = blockIdx.x * 256 + t;
    s[t] = (idx < N_NODES) ? deg[idx] : 0;
    __syncthreads();
    #pragma unroll
    for (int off = 128; off > 0; off >>= 1) {
        if (t < off) s[t] += s[t + off];
        __syncthreads();
    }
    if (t == 0) partials[blockIdx.x] = s[0];
}

__global__ __launch_bounds__(256) void scan_partials_kernel(int* __restrict__ partials) {
    __shared__ int s[256];
    const int t = threadIdx.x;
    const int v = (t < SCAN_B) ? partials[t] : 0;
    s[t] = v;
    __syncthreads();
    #pragma unroll
    for (int off = 1; off < 256; off <<= 1) {
        const int a = s[t];
        const int add = (t >= off) ? s[t - off] : 0;
        __syncthreads();
        s[t] = a + add;
        __syncthreads();
    }
    if (t < SCAN_B) partials[t] = s[t] - v;   // exclusive
}

__global__ __launch_bounds__(256) void scan_final_kernel(int* __restrict__ deg_cur,
                                                         int* __restrict__ offsets,
                                                         const int* __restrict__ partials) {
    __shared__ int s[256];
    const int t = threadIdx.x;
    const int idx = blockIdx.x * 256 + t;
    const int v = (idx < N_NODES) ? deg_cur[idx] : 0;
    s[t] = v;
    __syncthreads();
    #pragma unroll
    for (int off = 1; off < 256; off <<= 1) {
        const int a = s[t];
        const int add = (t >= off) ? s[t - off] : 0;
        __syncthreads();
        s[t] = a + add;
        __syncthreads();
    }
    const int excl = s[t] - v + partials[blockIdx.x];
    if (idx < N_NODES) {
        offsets[idx] = excl;
        deg_cur[idx] = excl;   // cursor for scatter
    }
    if (idx == 0) offsets[N_NODES] = N_EDGES;
}

// ---------------------------------------------------------------------------
// Kernel 4: scatter edge srcs into dst-sorted order via cursor bump.
// ---------------------------------------------------------------------------
__global__ __launch_bounds__(256) void scatter_sort_kernel(const int* __restrict__ ei,
                                                           int* __restrict__ cur,
                                                           int* __restrict__ sorted_src) {
    const int e = blockIdx.x * 256 + threadIdx.x;
    if (e < N_EDGES) {
        const int src = ei[e];
        const int dst = ei[N_EDGES + e];
        const int pos = atomicAdd(&cur[dst], 1);
        sorted_src[pos] = src;
    }
}

// ---------------------------------------------------------------------------
// Kernel 5: segment-reduce over bf16 xw. One wave per node; slot = lane>>4
// handles every 4th edge; (lane&15)*4 = channel group (ushort4 = 8 B/lane).
// fp32 accumulate, shfl_xor cross-slot reduce, fused bias + PReLU.
// ---------------------------------------------------------------------------
__global__ __launch_bounds__(256) void aggregate_kernel(const unsigned short* __restrict__ xwb,
                                                        const int* __restrict__ offsets,
                                                        const int* __restrict__ sorted_src,
                                                        const float* __restrict__ bias,
                                                        const float* __restrict__ prelu_a,
                                                        float* __restrict__ out) {
    const int wave = threadIdx.x >> 6;
    const int lane = threadIdx.x & 63;
    const int n = blockIdx.x * 4 + wave;
    if (n >= N_NODES) return;
    const int slot = lane >> 4;
    const int c0 = (lane & 15) * 4;
    const int beg = offsets[n];
    const int end = offsets[n + 1];

    float4 acc = make_float4(0.f, 0.f, 0.f, 0.f);
    for (int i = beg + slot; i < end; i += 4) {
        const int s = sorted_src[i];
        const ushort4 v = *(const ushort4*)(xwb + (size_t)s * HID_CH + c0);
        acc.x += bf2f(v.x); acc.y += bf2f(v.y);
        acc.z += bf2f(v.z); acc.w += bf2f(v.w);
    }
    acc.x += __shfl_xor(acc.x, 16, 64); acc.y += __shfl_xor(acc.y, 16, 64);
    acc.z += __shfl_xor(acc.z, 16, 64); acc.w += __shfl_xor(acc.w, 16, 64);
    acc.x += __shfl_xor(acc.x, 32, 64); acc.y += __shfl_xor(acc.y, 32, 64);
    acc.z += __shfl_xor(acc.z, 32, 64); acc.w += __shfl_xor(acc.w, 32, 64);

    if (slot == 0) {
        const float4 b = *(const float4*)(bias + c0);
        const float4 a = *(const float4*)(prelu_a + c0);
        float4 r;
        r.x = acc.x + b.x; r.x = r.x > 0.f ? r.x : a.x * r.x;
        r.y = acc.y + b.y; r.y = r.y > 0.f ? r.y : a.y * r.y;
        r.z = acc.z + b.z; r.z = r.z > 0.f ? r.z : a.z * r.z;
        r.w = acc.w + b.w; r.w = r.w > 0.f ? r.w : a.w * r.w;
        *(float4*)(out + (size_t)n * HID_CH + c0) = r;
    }
}

extern "C" void kernel_launch(void* const* d_in, const int* in_sizes, int n_in,
                              void* d_out, int out_size, void* d_ws, size_t ws_size,
                              hipStream_t stream) {
    const float* x       = (const float*)d_in[0];
    const int*   ei      = (const int*)d_in[1];   // [2, E]: src row then dst row
    const float* W       = (const float*)d_in[2];
    const float* bias    = (const float*)d_in[3];
    const float* prelu_a = (const float*)d_in[4];
    float* out = (float*)d_out;

    // workspace layout (16B-aligned offsets)
    char* w = (char*)d_ws;
    unsigned short* xwb      = (unsigned short*)(w);            // 6,400,000 B
    int*            cur      = (int*)(w + 6400000);             //   200,000 B
    int*            offsets  = (int*)(w + 6600192);             //   200,004 B
    int*            sorted   = (int*)(w + 6800384);             // 3,200,000 B
    int*            partials = (int*)(w + 10000384);            //       784 B
    unsigned short* wfrag    = (unsigned short*)(w + 10001168 + 14 /*pad->16*/);
    wfrag = (unsigned short*)(w + 10001184);                    //    32,768 B

    // 0) W -> bf16 B-fragments
    wfrag_kernel<<<8, 256, 0, stream>>>(W, wfrag);

    // 1) xwb = bf16(x @ W)
    gemm_kernel<<<(N_NODES + 63) / 64, 256, 0, stream>>>(x, wfrag, xwb);

    // 2) deg = 0; histogram over dst
    hipMemsetAsync(cur, 0, N_NODES * sizeof(int), stream);
    hist_kernel<<<(N_EDGES + 255) / 256, 256, 0, stream>>>(ei, cur);

    // 3) multi-block exclusive scan -> offsets, cursors
    scan_partial_kernel<<<SCAN_B, 256, 0, stream>>>(cur, partials);
    scan_partials_kernel<<<1, 256, 0, stream>>>(partials);
    scan_final_kernel<<<SCAN_B, 256, 0, stream>>>(cur, offsets, partials);

    // 4) dst-sort edge srcs
    scatter_sort_kernel<<<(N_EDGES + 255) / 256, 256, 0, stream>>>(ei, cur, sorted);

    // 5) segment-reduce + bias + PReLU
    aggregate_kernel<<<(N_NODES + 3) / 4, 256, 0, stream>>>(xwb, offsets, sorted, bias, prelu_a, out);
}